// Round 2
// baseline (51.823 us; speedup 1.0000x reference)
//
#include <hip/hip_runtime.h>
#include <stdint.h>

#define B_N 16
#define C_N 64
#define O_N 64
#define H_N 128
#define W_N 128

typedef short bf16x8 __attribute__((ext_vector_type(8)));
typedef float f32x4 __attribute__((ext_vector_type(4)));
typedef unsigned short u16;
typedef u16 u16x4 __attribute__((ext_vector_type(4)));

__device__ __forceinline__ u16 f2bf(float f) {
    uint32_t u = __float_as_uint(f);
    u += 0x7FFFu + ((u >> 16) & 1u);
    return (u16)(u >> 16);
}

// swz2: XOR bits 4-6 of the byte address with (w&7)^((w>>3)&7).
//  - b128 A-reads (16 consecutive w per lane group): each bank-quad hit
//    exactly 2x for aligned windows -> floor (free). jsh=+-1 windows: one
//    quad 3x -> ~1 extra cyc, negligible.
//  - b64 staging writes: (w>>3)&7 spans 8 values across a wave's w4 range ->
//    16 distinct b64 bank-starts -> 4 accesses/bank = b64 floor -> conflict-free
//    (was 16-way with the old (w&7)-only swizzle: 2.75M extra cycles/dispatch).
__device__ __forceinline__ int swz2(int w) { return ((w & 7) ^ ((w >> 3) & 7)) << 4; }

// Pre-gather weights into exact B-fragment order (coalesced reads version):
// wf[b][ij][cs][of][l][j8] (bf16); value = weight[b][c*9+ij][o],
// c = cs*32 + (l>>4)*8 + j8,  o = of*16 + (l&15).
// Thread handles one (b, c, ij, o4): f32x4 read along o (contiguous; adjacent
// ij blocks are also contiguous -> full coalescing), 4 scattered u16 writes.
__global__ __launch_bounds__(256) void prep_weights(const float* __restrict__ wt,
                                                    u16* __restrict__ wf) {
    int idx = blockIdx.x * 256 + threadIdx.x;   // 16*64*9*16 = 147456 total
    int e = idx;
    int o4 = e & 15; e >>= 4;
    int ij = e % 9;  e /= 9;
    int c  = e & 63; e >>= 6;
    int b  = e;
    f32x4 v = *reinterpret_cast<const f32x4*>(
        wt + ((size_t)b * 576 + (size_t)c * 9 + ij) * 64 + o4 * 4);
    const int cs = c >> 5, lgc = (c >> 3) & 3, j8 = c & 7;
#pragma unroll
    for (int k = 0; k < 4; ++k) {
        int o = o4 * 4 + k;
        int of = o >> 4, lrc = o & 15;
        size_t dst = ((size_t)((((b * 9 + ij) * 2 + cs) * 4 + of) * 64 + lgc * 16 + lrc)) * 8 + j8;
        wf[dst] = f2bf(v[k]);
    }
}

// Main kernel v3: one workgroup per (b, 4-row strip), grid 512 = 2 blocks/CU.
// Rows processed in PAIRS with staged-row-outer loops:
//  - A-fragment (s,jsh) loaded ONCE, feeds up to 2 rows x up to 2 i-taps
//    -> LDS b128 A-reads cut 1.5x (288 -> 192 per 2 rows).
//  - Weight set i (3 ij x 2cs x 2nf frags) loaded once per pair (rolling,
//    <=2 sets live) -> weight VMEM traffic halved vs per-row streaming.
//  - Circular 4-slot LDS; rows 4,5 restaged during pair 0 (loads issued one
//    segment before their ds_writes -> HBM latency hidden under MFMA).
__global__ __launch_bounds__(256, 2) void conv_main(const float* __restrict__ x,
                                                    const u16* __restrict__ wf,
                                                    const float* __restrict__ bias,
                                                    float* __restrict__ y) {
    __shared__ u16 xl[4 * 128 * 64];   // 4 row-slots x [w][c] bf16, 64KB, swz2

    // XCD-bijective swizzle: 512 wgs, 8 XCDs -> XCD j owns 2 full b's.
    const int lid = (blockIdx.x & 7) * 64 + (blockIdx.x >> 3);
    const int b = lid >> 5;
    const int h0 = (lid & 31) * 4;
    const int tid = threadIdx.x;

    const int wid = tid >> 6;
    const int l = tid & 63;
    const int wave_m = wid >> 1;
    const int wave_n = wid & 1;
    const int m0 = wave_m * 64;
    const int o0 = wave_n * 32;
    const int lr = l & 15;
    const int lg = l >> 4;

    const u16* wfb = wf + (size_t)b * (9 * 2 * 4 * 64 * 8);

    const float bv0 = bias[b * 64 + o0 + lr];
    const float bv1 = bias[b * 64 + o0 + 16 + lr];

    // ---- Prologue: stage rows s=0..3 (input rows h0-1..h0+2) ----
#pragma unroll
    for (int it = 0; it < 8; ++it) {
        int task = it * 256 + tid;            // < 2048
        int w4 = task & 31;
        int cq = (task >> 5) & 15;
        int s  = task >> 9;                   // 0..3
        int hr = (h0 + s + 127) & 127;
        const float* src = x + (((size_t)b * 64 + cq * 4) * 128 + hr) * 128 + w4 * 4;
        f32x4 L0 = *reinterpret_cast<const f32x4*>(src);
        f32x4 L1 = *reinterpret_cast<const f32x4*>(src + 16384);
        f32x4 L2 = *reinterpret_cast<const f32x4*>(src + 32768);
        f32x4 L3 = *reinterpret_cast<const f32x4*>(src + 49152);
#pragma unroll
        for (int j = 0; j < 4; ++j) {
            int w = w4 * 4 + j;
            u16x4 pk;
            pk.x = f2bf(L0[j]); pk.y = f2bf(L1[j]);
            pk.z = f2bf(L2[j]); pk.w = f2bf(L3[j]);
            int byte = s * 16384 + w * 128 + cq * 8;
            byte ^= swz2(w);
            *reinterpret_cast<u16x4*>(reinterpret_cast<char*>(xl) + byte) = pk;
        }
    }
    __syncthreads();

    f32x4 stA[8], stB[8];                     // restage in-flight registers

#pragma unroll
    for (int p = 0; p < 2; ++p) {
        const int r0 = 2 * p;
        bf16x8 ws[3][3][2][2];                // [i-set][jj][cs][nf], rolling
        f32x4 acc[2][4][2];
#pragma unroll
        for (int rl = 0; rl < 2; ++rl)
#pragma unroll
            for (int mf = 0; mf < 4; ++mf)
#pragma unroll
                for (int nf = 0; nf < 2; ++nf)
                    acc[rl][mf][nf] = (f32x4){0.f, 0.f, 0.f, 0.f};

#pragma unroll
        for (int k = 0; k < 4; ++k) {
            const int sg = r0 + k;            // global staged-row index

            // ---- restage pipeline (pair 0 only; rows 4,5 -> slots 0,1) ----
            if (p == 0 && k == 0) {
                const int hr = (h0 + 3) & 127;            // staged row 4
#pragma unroll
                for (int half = 0; half < 2; ++half) {
                    int task = half * 256 + tid;
                    int w4 = task & 31, cq = (task >> 5) & 15;
                    const float* src = x + (((size_t)b * 64 + cq * 4) * 128 + hr) * 128 + w4 * 4;
                    stA[half * 4 + 0] = *reinterpret_cast<const f32x4*>(src);
                    stA[half * 4 + 1] = *reinterpret_cast<const f32x4*>(src + 16384);
                    stA[half * 4 + 2] = *reinterpret_cast<const f32x4*>(src + 32768);
                    stA[half * 4 + 3] = *reinterpret_cast<const f32x4*>(src + 49152);
                }
            }
            if (p == 0 && k == 1) {
                // write row 4 -> slot 0 (slot free: BAR after k=0)
#pragma unroll
                for (int half = 0; half < 2; ++half) {
                    int task = half * 256 + tid;
                    int w4 = task & 31, cq = (task >> 5) & 15;
#pragma unroll
                    for (int j = 0; j < 4; ++j) {
                        int w = w4 * 4 + j;
                        u16x4 pk;
                        pk.x = f2bf(stA[half * 4 + 0][j]); pk.y = f2bf(stA[half * 4 + 1][j]);
                        pk.z = f2bf(stA[half * 4 + 2][j]); pk.w = f2bf(stA[half * 4 + 3][j]);
                        int byte = 0 * 16384 + w * 128 + cq * 8;
                        byte ^= swz2(w);
                        *reinterpret_cast<u16x4*>(reinterpret_cast<char*>(xl) + byte) = pk;
                    }
                }
                const int hr = (h0 + 4) & 127;            // staged row 5
#pragma unroll
                for (int half = 0; half < 2; ++half) {
                    int task = half * 256 + tid;
                    int w4 = task & 31, cq = (task >> 5) & 15;
                    const float* src = x + (((size_t)b * 64 + cq * 4) * 128 + hr) * 128 + w4 * 4;
                    stB[half * 4 + 0] = *reinterpret_cast<const f32x4*>(src);
                    stB[half * 4 + 1] = *reinterpret_cast<const f32x4*>(src + 16384);
                    stB[half * 4 + 2] = *reinterpret_cast<const f32x4*>(src + 32768);
                    stB[half * 4 + 3] = *reinterpret_cast<const f32x4*>(src + 49152);
                }
            }
            if (p == 0 && k == 2) {
                // write row 5 -> slot 1 (slot free: BAR after k=1)
#pragma unroll
                for (int half = 0; half < 2; ++half) {
                    int task = half * 256 + tid;
                    int w4 = task & 31, cq = (task >> 5) & 15;
#pragma unroll
                    for (int j = 0; j < 4; ++j) {
                        int w = w4 * 4 + j;
                        u16x4 pk;
                        pk.x = f2bf(stB[half * 4 + 0][j]); pk.y = f2bf(stB[half * 4 + 1][j]);
                        pk.z = f2bf(stB[half * 4 + 2][j]); pk.w = f2bf(stB[half * 4 + 3][j]);
                        int byte = 1 * 16384 + w * 128 + cq * 8;
                        byte ^= swz2(w);
                        *reinterpret_cast<u16x4*>(reinterpret_cast<char*>(xl) + byte) = pk;
                    }
                }
            }

            // ---- weight set k load (ij = k*3 + jj); first use this segment,
            //      ordered after earlier sets' MFMAs -> L2 latency hidden ----
            if (k < 3) {
#pragma unroll
                for (int jj = 0; jj < 3; ++jj)
#pragma unroll
                    for (int cs = 0; cs < 2; ++cs)
#pragma unroll
                        for (int nf = 0; nf < 2; ++nf) {
                            const int ij = k * 3 + jj;
                            ws[k][jj][cs][nf] = *reinterpret_cast<const bf16x8*>(
                                wfb + (size_t)((ij * 2 + cs) * 4 + wave_n * 2 + nf) * 512 + l * 8);
                        }
            }

            // ---- compute segment: staged row sg feeds rows r = sg-i ----
            const int rbase = (sg & 3) * 16384;
#pragma unroll
            for (int jp = 0; jp < 3; ++jp) {
                const int jsh = jp - 1;
#pragma unroll
                for (int cs = 0; cs < 2; ++cs) {
                    bf16x8 afr[4];
                    const int cb = cs * 64 + lg * 16;
#pragma unroll
                    for (int mf = 0; mf < 4; ++mf) {
                        int w = (m0 + mf * 16 + lr + jsh + 128) & 127;
                        int byte = rbase + w * 128 + cb;
                        byte ^= swz2(w);
                        afr[mf] = *reinterpret_cast<const bf16x8*>(
                            reinterpret_cast<const char*>(xl) + byte);
                    }
#pragma unroll
                    for (int i = 0; i < 3; ++i) {
                        if (k - i == 0 || k - i == 1) {   // compile-time pruned
                            const int rl = k - i;
#pragma unroll
                            for (int mf = 0; mf < 4; ++mf) {
                                acc[rl][mf][0] = __builtin_amdgcn_mfma_f32_16x16x32_bf16(
                                    afr[mf], ws[i][jp][cs][0], acc[rl][mf][0], 0, 0, 0);
                                acc[rl][mf][1] = __builtin_amdgcn_mfma_f32_16x16x32_bf16(
                                    afr[mf], ws[i][jp][cs][1], acc[rl][mf][1], 0, 0, 0);
                            }
                        }
                    }
                }
            }

            if (p == 0 && k < 3) __syncthreads();

            // row r0 complete after segment k=2: store early, frees 32 regs
            if (k == 2) {
                const int h = h0 + r0;
#pragma unroll
                for (int nf = 0; nf < 2; ++nf) {
                    int o = o0 + nf * 16 + lr;
                    float bv = nf ? bv1 : bv0;
#pragma unroll
                    for (int mf = 0; mf < 4; ++mf) {
                        int w0 = m0 + mf * 16 + lg * 4;
                        float* dst = y + (((size_t)b * 64 + o) * 128 + h) * 128 + w0;
                        f32x4 out;
                        out[0] = acc[0][mf][nf][0] + bv;
                        out[1] = acc[0][mf][nf][1] + bv;
                        out[2] = acc[0][mf][nf][2] + bv;
                        out[3] = acc[0][mf][nf][3] + bv;
                        *reinterpret_cast<f32x4*>(dst) = out;
                    }
                }
            }
        }
        // row r0+1 complete after segment k=3
        {
            const int h = h0 + r0 + 1;
#pragma unroll
            for (int nf = 0; nf < 2; ++nf) {
                int o = o0 + nf * 16 + lr;
                float bv = nf ? bv1 : bv0;
#pragma unroll
                for (int mf = 0; mf < 4; ++mf) {
                    int w0 = m0 + mf * 16 + lg * 4;
                    float* dst = y + (((size_t)b * 64 + o) * 128 + h) * 128 + w0;
                    f32x4 out;
                    out[0] = acc[1][mf][nf][0] + bv;
                    out[1] = acc[1][mf][nf][1] + bv;
                    out[2] = acc[1][mf][nf][2] + bv;
                    out[3] = acc[1][mf][nf][3] + bv;
                    *reinterpret_cast<f32x4*>(dst) = out;
                }
            }
        }
    }
}

// Correctness-insurance fallback if workspace is too small (should not trigger).
__global__ void naive_conv(const float* __restrict__ x, const float* __restrict__ wt,
                           const float* __restrict__ bias, float* __restrict__ y) {
    int w = threadIdx.x;
    int h = blockIdx.x & 127;
    int o = (blockIdx.x >> 7) & 63;
    int b = blockIdx.x >> 13;
    float s = bias[b * 64 + o];
    for (int c = 0; c < 64; ++c)
        for (int i = 0; i < 3; ++i)
            for (int j = 0; j < 3; ++j) {
                int hh = (h + i + 127) & 127;
                int ww = (w + j + 127) & 127;
                s += x[(((size_t)b * 64 + c) * 128 + hh) * 128 + ww] *
                     wt[((size_t)b * 576 + (size_t)(c * 9 + i * 3 + j)) * 64 + o];
            }
    y[(((size_t)b * 64 + o) * 128 + h) * 128 + w] = s;
}

extern "C" void kernel_launch(void* const* d_in, const int* in_sizes, int n_in,
                              void* d_out, int out_size, void* d_ws, size_t ws_size,
                              hipStream_t stream) {
    const float* x    = (const float*)d_in[0];
    const float* wt   = (const float*)d_in[1];
    const float* bias = (const float*)d_in[2];
    float* y = (float*)d_out;

    const size_t WF_ELEMS = (size_t)B_N * 9 * 2 * 4 * 64 * 8;   // 589824
    const size_t WF_BYTES = WF_ELEMS * sizeof(u16);             // 1.18 MB

    if (ws_size >= WF_BYTES) {
        u16* wf = (u16*)d_ws;
        hipLaunchKernelGGL(prep_weights, dim3(576), dim3(256), 0, stream, wt, wf);
        hipLaunchKernelGGL(conv_main, dim3(B_N * H_N / 4), dim3(256), 0, stream, x, wf, bias, y);
    } else {
        hipLaunchKernelGGL(naive_conv, dim3(B_N * O_N * H_N), dim3(128), 0, stream, x, wt, bias, y);
    }
}